// Round 15
// baseline (489.194 us; speedup 1.0000x reference)
//
#include <hip/hip_runtime.h>

typedef unsigned short u16;
typedef __attribute__((ext_vector_type(8))) short bf16x8;
typedef __attribute__((ext_vector_type(4))) float f32x4;
typedef __attribute__((ext_vector_type(4))) int   i32x4;
typedef __attribute__((ext_vector_type(4))) unsigned short u16x4;

#define DM 1024

__device__ __forceinline__ float bf2f(u16 u){
  union { unsigned int i; float f; } v; v.i = ((unsigned int)u)<<16; return v.f;
}
__device__ __forceinline__ u16 f2bf(float f){
  unsigned int x = __float_as_uint(f);
  return (u16)((x + 0x7FFFu + ((x>>16)&1u)) >> 16);   // RNE, finite inputs only
}

// ---------------- K0: fused weight-quantize (blocks 0..1023) + x->bf16 (rest) -------
// wq (bf16) rows: [0,1024) = R ; [1024,3072) = K[d],V[d] interleaved.
// wq8 (i8)  rows: [0,1024) = O (ternary exact in i8).  wsc: all 4096 rows.
__global__ __launch_bounds__(256)
void init_pack(const float* __restrict__ W0, const float* __restrict__ W1,
               const float* __restrict__ W2, const float* __restrict__ W3,
               const float* __restrict__ x,
               u16* __restrict__ wq, signed char* __restrict__ wq8,
               float* __restrict__ wsc, u16* __restrict__ xb)
{
  if (blockIdx.x >= 1024){                     // ---- x f32 -> bf16 ----
    const int i = ((blockIdx.x-1024)*256 + threadIdx.x)*4;
    float4 v = *(const float4*)&x[i];
    u16x4 o; o[0]=f2bf(v.x); o[1]=f2bf(v.y); o[2]=f2bf(v.z); o[3]=f2bf(v.w);
    *(u16x4*)&xb[i] = o;
    return;
  }
  const int gr   = blockIdx.x*4 + (threadIdx.x>>6);  // output row 0..4095 (wave-uniform)
  const int lane = threadIdx.x & 63;
  const float* W; int row;
  if (gr < 1024)      { W = W0; row = gr; }
  else if (gr < 3072) { row = (gr-1024)>>1; W = (gr&1) ? W2 : W1; }
  else                { W = W3; row = gr-3072; }
  const float* wr = W + (size_t)row*DM;
  float4 v[4]; float s = 0.f;
  #pragma unroll
  for (int c=0;c<4;c++){
    v[c] = *(const float4*)&wr[c*256 + lane*4];
    s += fabsf(v[c].x)+fabsf(v[c].y)+fabsf(v[c].z)+fabsf(v[c].w);
  }
  #pragma unroll
  for (int off=32; off; off>>=1) s += __shfl_down(s, off);
  s = __shfl(s, 0);
  const float scale = fmaxf(s*(1.f/1024.f), 1e-5f);
  if (lane==0) wsc[gr] = scale;
  if (gr < 3072){
    u16* wo = wq + (size_t)gr*DM;
    #pragma unroll
    for (int c=0;c<4;c++){
      u16x4 q;
      q[0] = f2bf(fminf(fmaxf(rintf(v[c].x/scale),-1.f),1.f));
      q[1] = f2bf(fminf(fmaxf(rintf(v[c].y/scale),-1.f),1.f));
      q[2] = f2bf(fminf(fmaxf(rintf(v[c].z/scale),-1.f),1.f));
      q[3] = f2bf(fminf(fmaxf(rintf(v[c].w/scale),-1.f),1.f));
      *(u16x4*)&wo[c*256 + lane*4] = q;
    }
  } else {
    signed char* wo = wq8 + (size_t)(gr-3072)*DM;
    #pragma unroll
    for (int c=0;c<4;c++){
      const int q0 = (int)rintf(fminf(fmaxf(v[c].x/scale,-1.f),1.f));
      const int q1 = (int)rintf(fminf(fmaxf(v[c].y/scale,-1.f),1.f));
      const int q2 = (int)rintf(fminf(fmaxf(v[c].z/scale,-1.f),1.f));
      const int q3 = (int)rintf(fminf(fmaxf(v[c].w/scale,-1.f),1.f));
      const unsigned int p = (q0&0xFF) | ((q1&0xFF)<<8) | ((q2&0xFF)<<16) | ((unsigned)(q3&0xFF)<<24);
      *(unsigned int*)&wo[c*256 + lane*4] = p;
    }
  }
}

// ---------------- K2: m97-style 128x128 single-buffer bf16 GEMM (912 TF) ------------
// N=3072; cols<1024 -> sigmoid -> r ; cols>=1024 interleaved k/v -> kv product.
#define RD(base, off) (*(const bf16x8*)((const char*)(base) + (off)))

__global__ __launch_bounds__(256, 4)
void gemm_rkv(const u16* __restrict__ Ag, const u16* __restrict__ Bq,
              const float* __restrict__ bscale,
              u16* __restrict__ o_r, u16* __restrict__ o_kv)
{
  __shared__ u16 sA[128*64];
  __shared__ u16 sB[128*64];
  const int tid = threadIdx.x, wave = tid>>6, lane = tid&63;
  const int lr = lane&15, lg = lane>>4;
  const int wm = wave>>1, wn = wave&1;
  const int bm0 = blockIdx.x*128, bn0 = blockIdx.y*128;
  constexpr int nt = 16;

  const int r8   = lane>>3;
  const int scol = ((lane&7)<<4) ^ (r8<<4);
  const size_t aoff = (size_t)(bm0 + wave*8 + r8)*2048 + scol;
  const size_t boff = (size_t)(bn0 + wave*8 + r8)*2048 + scol;
  const int ldst = wave*1024;

  const int S = (lr&7)<<4;
  const int koff0 = ((lg<<4)     ) ^ S;
  const int koff1 = (64 + (lg<<4)) ^ S;
  const int arow = (wm*64 + lr)*128;
  const int brow = (wn*64 + lr)*128;

  f32x4 acc[4][4];
  #pragma unroll
  for (int i=0;i<4;i++)
    #pragma unroll
    for (int j=0;j<4;j++) acc[i][j] = (f32x4){0.f,0.f,0.f,0.f};

  for (int t=0; t<nt; ++t){
    #pragma unroll
    for (int q=0;q<4;q++){
      __builtin_amdgcn_global_load_lds(
        (const __attribute__((address_space(1))) void*)((const char*)Ag + aoff + q*65536 + (size_t)t*128),
        (__attribute__((address_space(3))) void*)((char*)sA + ldst + q*4096), 16, 0, 0);
      __builtin_amdgcn_global_load_lds(
        (const __attribute__((address_space(1))) void*)((const char*)Bq + boff + q*65536 + (size_t)t*128),
        (__attribute__((address_space(3))) void*)((char*)sB + ldst + q*4096), 16, 0, 0);
    }
    __syncthreads();
    {
      bf16x8 a[4], b[4];
      #pragma unroll
      for (int m=0;m<4;m++) a[m] = RD(sA, arow + m*2048 + koff0);
      #pragma unroll
      for (int n=0;n<4;n++) b[n] = RD(sB, brow + n*2048 + koff0);
      #pragma unroll
      for (int m=0;m<4;m++)
        #pragma unroll
        for (int n=0;n<4;n++)
          acc[m][n] = __builtin_amdgcn_mfma_f32_16x16x32_bf16(a[m], b[n], acc[m][n], 0,0,0);
      #pragma unroll
      for (int m=0;m<4;m++) a[m] = RD(sA, arow + m*2048 + koff1);
      #pragma unroll
      for (int n=0;n<4;n++) b[n] = RD(sB, brow + n*2048 + koff1);
      #pragma unroll
      for (int m=0;m<4;m++)
        #pragma unroll
        for (int n=0;n<4;n++)
          acc[m][n] = __builtin_amdgcn_mfma_f32_16x16x32_bf16(a[m], b[n], acc[m][n], 0,0,0);
    }
    __syncthreads();
  }

  #pragma unroll
  for (int mi=0; mi<4; ++mi){
    #pragma unroll
    for (int ni=0; ni<4; ++ni){
      const int col = bn0 + wn*64 + ni*16 + lr;
      const float sc = bscale[col];
      const int rowb = bm0 + wm*64 + mi*16 + lg*4;
      const f32x4 a = acc[mi][ni];
      if (bn0 < 1024){
        #pragma unroll
        for (int r2=0;r2<4;r2++){
          const float val = a[r2]*sc;
          o_r[(size_t)(rowb+r2)*DM + col] = f2bf(1.f/(1.f+expf(-val)));
        }
      } else {
        const int dv = (col - 1024) >> 1;
        #pragma unroll
        for (int r2=0;r2<4;r2++){
          const float val = a[r2]*sc;
          const float pr  = val * __shfl_xor(val, 1);
          if (!(lr & 1))
            o_kv[(size_t)(rowb+r2)*DM + dv] = f2bf(pr);
        }
      }
    }
  }
}

// ---------------- K6: i8 GEMM for the Wo projection (2x MFMA rate, exact i32 acc) ----
#define RD8(base, off) (*(const i32x4*)((const char*)(base) + (off)))

__global__ __launch_bounds__(256, 4)
void gemm_o8(const signed char* __restrict__ Ag, const signed char* __restrict__ Bq,
             const float* __restrict__ bscale, const float* __restrict__ sxr,
             float* __restrict__ o_f)
{
  __shared__ signed char sA[128*128];           // 16KB
  __shared__ signed char sB[128*128];           // 16KB
  const int tid = threadIdx.x, wave = tid>>6, lane = tid&63;
  const int lr = lane&15, lg = lane>>4;
  const int wm = wave>>1, wn = wave&1;
  const int bm0 = blockIdx.x*128, bn0 = blockIdx.y*128;
  constexpr int nt = 8;                         // K = 1024 i8 / 128B

  const int r8   = lane>>3;
  const int scol = ((lane&7)<<4) ^ (r8<<4);
  const size_t aoff = (size_t)(bm0 + wave*8 + r8)*1024 + scol;
  const size_t boff = (size_t)(bn0 + wave*8 + r8)*1024 + scol;
  const int ldst = wave*1024;

  const int S = (lr&7)<<4;
  const int koff0 = ((lg<<4)     ) ^ S;
  const int koff1 = (64 + (lg<<4)) ^ S;
  const int arow = (wm*64 + lr)*128;
  const int brow = (wn*64 + lr)*128;

  i32x4 acc[4][4];
  #pragma unroll
  for (int i=0;i<4;i++)
    #pragma unroll
    for (int j=0;j<4;j++) acc[i][j] = (i32x4){0,0,0,0};

  for (int t=0; t<nt; ++t){
    #pragma unroll
    for (int q=0;q<4;q++){
      __builtin_amdgcn_global_load_lds(
        (const __attribute__((address_space(1))) void*)((const char*)Ag + aoff + q*32768 + (size_t)t*128),
        (__attribute__((address_space(3))) void*)((char*)sA + ldst + q*4096), 16, 0, 0);
      __builtin_amdgcn_global_load_lds(
        (const __attribute__((address_space(1))) void*)((const char*)Bq + boff + q*32768 + (size_t)t*128),
        (__attribute__((address_space(3))) void*)((char*)sB + ldst + q*4096), 16, 0, 0);
    }
    __syncthreads();
    {
      i32x4 a[4], b[4];
      #pragma unroll
      for (int m=0;m<4;m++) a[m] = RD8(sA, arow + m*2048 + koff0);
      #pragma unroll
      for (int n=0;n<4;n++) b[n] = RD8(sB, brow + n*2048 + koff0);
      #pragma unroll
      for (int m=0;m<4;m++)
        #pragma unroll
        for (int n=0;n<4;n++)
          acc[m][n] = __builtin_amdgcn_mfma_i32_16x16x64_i8(a[m], b[n], acc[m][n], 0,0,0);
      #pragma unroll
      for (int m=0;m<4;m++) a[m] = RD8(sA, arow + m*2048 + koff1);
      #pragma unroll
      for (int n=0;n<4;n++) b[n] = RD8(sB, brow + n*2048 + koff1);
      #pragma unroll
      for (int m=0;m<4;m++)
        #pragma unroll
        for (int n=0;n<4;n++)
          acc[m][n] = __builtin_amdgcn_mfma_i32_16x16x64_i8(a[m], b[n], acc[m][n], 0,0,0);
    }
    __syncthreads();
  }

  #pragma unroll
  for (int mi=0; mi<4; ++mi){
    const int rowb = bm0 + wm*64 + mi*16 + lg*4;
    float sx[4];
    #pragma unroll
    for (int r2=0;r2<4;r2++) sx[r2] = sxr[rowb+r2];
    #pragma unroll
    for (int ni=0; ni<4; ++ni){
      const int col = bn0 + wn*64 + ni*16 + lr;
      const float sc = bscale[col];
      const i32x4 a = acc[mi][ni];
      #pragma unroll
      for (int r2=0;r2<4;r2++)
        o_f[(size_t)(rowb+r2)*DM + col] = (float)a[r2] * sx[r2] * sc;
    }
  }
}

// ---------------- K3+K4+K5 fused: chunk-sum -> grid sync -> prefix -> scan ----------
// 512 blocks (b 0..3 x c 0..127), all co-resident (3+ blocks/CU capacity at this
// VGPR/LDS footprint >= 768 > 512; every block completes phase A before any wait ->
// progress guaranteed).  part prefix computed by blocks c==0 in the SAME per-d
// sequential order as the old chunk_prefix kernel -> bit-identical results.
// cnt/flag zeroed via hipMemsetAsync each call (deterministic, no cross-call state).
__global__ __launch_bounds__(256)
void scan_fused(const u16* __restrict__ kv, const u16* __restrict__ rbuf,
                float* __restrict__ part, const float* __restrict__ decay,
                const float* __restrict__ lnw, signed char* __restrict__ yn8,
                float* __restrict__ sxr,
                unsigned int* __restrict__ cnt, unsigned int* __restrict__ flag)
{
  const int c = blockIdx.x & 127, b = blockIdx.x >> 7;
  const int tid = threadIdx.x, lane = tid&63, wave = tid>>6;
  const int d0 = tid*4;
  __shared__ float redS[2][4];
  __shared__ float redM[2][4];

  float lw[4], E1[4], E1i[4], e0[4], rc0[4];
  #pragma unroll
  for (int j=0;j<4;j++){
    const float dec = 1.f/(1.f+expf(-decay[d0+j]));
    const float ld  = logf(fmaxf(dec, 1e-7f));
    lw[j]  = lnw[d0+j];
    E1[j]  = expf(ld);
    E1i[j] = expf(-ld);
    e0[j]  = expf((float)(c*32)*ld);            // underflows to 0 like ref
    rc0[j] = expf(-(float)(c*32)*ld);           // inf ok -> clipped
  }

  // ---- phase A: chunk sum; cache the 32 kv rows in registers ----
  u16x4 kvr[32];
  {
    f32x4 sum = {0.f,0.f,0.f,0.f};
    float rca[4] = {rc0[0],rc0[1],rc0[2],rc0[3]};
    #pragma unroll
    for (int s=0;s<32;s++){
      kvr[s] = *(const u16x4*)&kv[((size_t)(b*4096 + c*32 + s))*DM + d0];
      #pragma unroll
      for (int j=0;j<4;j++){
        sum[j] += bf2f(kvr[s][j]) * fminf(rca[j], 1e10f);
        rca[j] *= E1i[j];
      }
    }
    *(f32x4*)&part[((size_t)(b*128+c))*DM + d0] = sum;
  }
  __threadfence();                              // make part row device-visible
  __syncthreads();
  if (tid==0)
    __hip_atomic_fetch_add(&cnt[b], 1u, __ATOMIC_ACQ_REL, __HIP_MEMORY_SCOPE_AGENT);

  // ---- phase B (blocks c==0 only): exclusive prefix for batch b, in-place ----
  if (c == 0){
    if (tid==0){
      while (__hip_atomic_load(&cnt[b], __ATOMIC_ACQUIRE, __HIP_MEMORY_SCOPE_AGENT) < 128u)
        __builtin_amdgcn_s_sleep(8);
    }
    __syncthreads();
    __threadfence();                            // acquire: invalidate stale L1
    f32x4 run2 = {0.f,0.f,0.f,0.f};
    for (int c8=0; c8<128; c8+=8){
      f32x4 v[8];
      #pragma unroll
      for (int i=0;i<8;i++)
        v[i] = *(const f32x4*)&part[((size_t)(b*128+c8+i))*DM + d0];
      #pragma unroll
      for (int i=0;i<8;i++){                    // ascending order (bit-exact per d)
        const f32x4 tmp = v[i];
        *(f32x4*)&part[((size_t)(b*128+c8+i))*DM + d0] = run2;
        run2 += tmp;
      }
    }
    __threadfence();
    __syncthreads();
    if (tid==0)
      __hip_atomic_store(&flag[b], 1u, __ATOMIC_RELEASE, __HIP_MEMORY_SCOPE_AGENT);
  }

  // ---- wait for prefix, then acquire ----
  if (tid==0){
    while (__hip_atomic_load(&flag[b], __ATOMIC_ACQUIRE, __HIP_MEMORY_SCOPE_AGENT) == 0u)
      __builtin_amdgcn_s_sleep(16);
  }
  __syncthreads();
  __threadfence();                              // L1 inv for all threads' part read

  // ---- phase C: scan + y=r*state + rmsnorm -> i8 yn (per-row scale) ----
  f32x4 run = *(const f32x4*)&part[((size_t)(b*128+c))*DM + d0];
  float e[4]  = {e0[0], e0[1], e0[2], e0[3]};
  float rc[4] = {rc0[0],rc0[1],rc0[2],rc0[3]};
  #pragma unroll
  for (int s=0;s<32;s++){
    const int t = c*32 + s;
    const size_t base = ((size_t)(b*4096+t))*DM + d0;
    const u16x4 r4 = *(const u16x4*)&rbuf[base];
    float yl[4]; float ss = 0.f, mx = 0.f;
    #pragma unroll
    for (int j=0;j<4;j++){
      run[j] += bf2f(kvr[s][j]) * fminf(rc[j], 1e10f);
      const float st = run[j]*e[j];             // chained e: monotone underflow to 0
      const float y = bf2f(r4[j])*st;
      ss += y*y;
      yl[j] = y*lw[j];
      mx = fmaxf(mx, fabsf(yl[j]));
      rc[j] *= E1i[j];
      e[j]  *= E1[j];
    }
    #pragma unroll
    for (int off=32; off; off>>=1){
      ss += __shfl_down(ss, off);
      mx  = fmaxf(mx, __shfl_down(mx, off));
    }
    if (lane==0){ redS[s&1][wave] = ss; redM[s&1][wave] = mx; }
    __syncthreads();
    const float tot = (redS[s&1][0]+redS[s&1][1])+(redS[s&1][2]+redS[s&1][3]);
    const float m1  = fmaxf(fmaxf(redM[s&1][0],redM[s&1][1]),
                            fmaxf(redM[s&1][2],redM[s&1][3]));
    const float rs  = 1.f/sqrtf(tot*(1.f/1024.f) + 1e-6f);
    const float m1s = fmaxf(m1, 1e-30f);
    const float qk  = 127.f/m1s;
    if (tid==0) sxr[b*4096+t] = m1s*rs*(1.f/127.f);
    unsigned int p = 0;
    #pragma unroll
    for (int j=0;j<4;j++){
      int q = (int)rintf(yl[j]*qk);
      q = q>127?127:(q<-127?-127:q);
      p |= ((unsigned)(q&0xFF)) << (8*j);
    }
    *(unsigned int*)&yn8[base] = p;
  }
}

extern "C" void kernel_launch(void* const* d_in, const int* in_sizes, int n_in,
                              void* d_out, int out_size, void* d_ws, size_t ws_size,
                              hipStream_t stream)
{
  (void)in_sizes; (void)n_in; (void)out_size; (void)ws_size;
  const float* x    = (const float*)d_in[0];
  const float* Wr   = (const float*)d_in[1];
  const float* Wk   = (const float*)d_in[2];
  const float* Wv   = (const float*)d_in[3];
  const float* Wo   = (const float*)d_in[4];
  const float* dec  = (const float*)d_in[5];
  const float* lnw  = (const float*)d_in[6];

  // layout: wq 6MB | wq8 1MB | wsc 16KB | rbuf 33.5MB | kvbuf 33.5MB | part 2MB |
  //         xb 33.5MB | yn8 16.8MB | sxr 64KB | sync 64B
  char* ws = (char*)d_ws;
  u16*          wq    = (u16*)(ws + 0);
  signed char*  wq8   = (signed char*)(ws + 6291456);
  float*        wsc   = (float*)(ws + 7340032);
  u16*          rbuf  = (u16*)(ws + 7356416);
  u16*          kvbuf = (u16*)(ws + 40910848);
  float*        part  = (float*)(ws + 74465280);
  u16*          xb    = (u16*)(ws + 76562432);
  signed char*  yn8   = (signed char*)(ws + 110116864);
  float*        sxr   = (float*)(ws + 126894080);
  unsigned int* cnt   = (unsigned int*)(ws + 126959616);   // [4]
  unsigned int* flag  = (unsigned int*)(ws + 126959648);   // [4]

  hipMemsetAsync(ws + 126959616, 0, 64, stream);           // zero cnt+flag each call
  init_pack<<<17408, 256, 0, stream>>>(Wr, Wk, Wv, Wo, x, wq, wq8, wsc, xb);
  gemm_rkv<<<dim3(128,24), 256, 0, stream>>>(xb, wq, wsc, rbuf, kvbuf);
  scan_fused<<<512, 256, 0, stream>>>(kvbuf, rbuf, part, dec, lnw, yn8, sxr, cnt, flag);
  gemm_o8<<<dim3(128,8), 256, 0, stream>>>(yn8, wq8, wsc + 3072, sxr, (float*)d_out);
}

// Round 16
// 203.296 us; speedup vs baseline: 2.4063x; 2.4063x over previous
//
#include <hip/hip_runtime.h>

typedef unsigned short u16;
typedef __attribute__((ext_vector_type(8))) short bf16x8;
typedef __attribute__((ext_vector_type(4))) float f32x4;
typedef __attribute__((ext_vector_type(4))) int   i32x4;
typedef __attribute__((ext_vector_type(4))) unsigned short u16x4;

#define DM 1024

__device__ __forceinline__ float bf2f(u16 u){
  union { unsigned int i; float f; } v; v.i = ((unsigned int)u)<<16; return v.f;
}
__device__ __forceinline__ u16 f2bf(float f){
  unsigned int x = __float_as_uint(f);
  return (u16)((x + 0x7FFFu + ((x>>16)&1u)) >> 16);   // RNE, finite inputs only
}

// ---------------- K0: fused weight-quantize (blocks 0..1023) + x->bf16 (rest) -------
// wq (bf16) rows: [0,1024) = R ; [1024,3072) = K[d],V[d] interleaved.
// wq8 (i8)  rows: [0,1024) = O (ternary exact in i8).  wsc: all 4096 rows.
__global__ __launch_bounds__(256)
void init_pack(const float* __restrict__ W0, const float* __restrict__ W1,
               const float* __restrict__ W2, const float* __restrict__ W3,
               const float* __restrict__ x,
               u16* __restrict__ wq, signed char* __restrict__ wq8,
               float* __restrict__ wsc, u16* __restrict__ xb)
{
  if (blockIdx.x >= 1024){                     // ---- x f32 -> bf16 ----
    const int i = ((blockIdx.x-1024)*256 + threadIdx.x)*4;
    float4 v = *(const float4*)&x[i];
    u16x4 o; o[0]=f2bf(v.x); o[1]=f2bf(v.y); o[2]=f2bf(v.z); o[3]=f2bf(v.w);
    *(u16x4*)&xb[i] = o;
    return;
  }
  const int gr   = blockIdx.x*4 + (threadIdx.x>>6);  // output row 0..4095 (wave-uniform)
  const int lane = threadIdx.x & 63;
  const float* W; int row;
  if (gr < 1024)      { W = W0; row = gr; }
  else if (gr < 3072) { row = (gr-1024)>>1; W = (gr&1) ? W2 : W1; }
  else                { W = W3; row = gr-3072; }
  const float* wr = W + (size_t)row*DM;
  float4 v[4]; float s = 0.f;
  #pragma unroll
  for (int c=0;c<4;c++){
    v[c] = *(const float4*)&wr[c*256 + lane*4];
    s += fabsf(v[c].x)+fabsf(v[c].y)+fabsf(v[c].z)+fabsf(v[c].w);
  }
  #pragma unroll
  for (int off=32; off; off>>=1) s += __shfl_down(s, off);
  s = __shfl(s, 0);
  const float scale = fmaxf(s*(1.f/1024.f), 1e-5f);
  if (lane==0) wsc[gr] = scale;
  if (gr < 3072){
    u16* wo = wq + (size_t)gr*DM;
    #pragma unroll
    for (int c=0;c<4;c++){
      u16x4 q;
      q[0] = f2bf(fminf(fmaxf(rintf(v[c].x/scale),-1.f),1.f));
      q[1] = f2bf(fminf(fmaxf(rintf(v[c].y/scale),-1.f),1.f));
      q[2] = f2bf(fminf(fmaxf(rintf(v[c].z/scale),-1.f),1.f));
      q[3] = f2bf(fminf(fmaxf(rintf(v[c].w/scale),-1.f),1.f));
      *(u16x4*)&wo[c*256 + lane*4] = q;
    }
  } else {
    signed char* wo = wq8 + (size_t)(gr-3072)*DM;
    #pragma unroll
    for (int c=0;c<4;c++){
      const int q0 = (int)rintf(fminf(fmaxf(v[c].x/scale,-1.f),1.f));
      const int q1 = (int)rintf(fminf(fmaxf(v[c].y/scale,-1.f),1.f));
      const int q2 = (int)rintf(fminf(fmaxf(v[c].z/scale,-1.f),1.f));
      const int q3 = (int)rintf(fminf(fmaxf(v[c].w/scale,-1.f),1.f));
      const unsigned int p = (q0&0xFF) | ((q1&0xFF)<<8) | ((q2&0xFF)<<16) | ((unsigned)(q3&0xFF)<<24);
      *(unsigned int*)&wo[c*256 + lane*4] = p;
    }
  }
}

// ---------------- K2: m97-style 128x128 single-buffer bf16 GEMM (912 TF) ------------
// N=3072; cols<1024 -> sigmoid -> r ; cols>=1024 interleaved k/v -> kv product.
#define RD(base, off) (*(const bf16x8*)((const char*)(base) + (off)))

__global__ __launch_bounds__(256, 4)
void gemm_rkv(const u16* __restrict__ Ag, const u16* __restrict__ Bq,
              const float* __restrict__ bscale,
              u16* __restrict__ o_r, u16* __restrict__ o_kv)
{
  __shared__ u16 sA[128*64];
  __shared__ u16 sB[128*64];
  const int tid = threadIdx.x, wave = tid>>6, lane = tid&63;
  const int lr = lane&15, lg = lane>>4;
  const int wm = wave>>1, wn = wave&1;
  const int bm0 = blockIdx.x*128, bn0 = blockIdx.y*128;
  constexpr int nt = 16;

  const int r8   = lane>>3;
  const int scol = ((lane&7)<<4) ^ (r8<<4);
  const size_t aoff = (size_t)(bm0 + wave*8 + r8)*2048 + scol;
  const size_t boff = (size_t)(bn0 + wave*8 + r8)*2048 + scol;
  const int ldst = wave*1024;

  const int S = (lr&7)<<4;
  const int koff0 = ((lg<<4)     ) ^ S;
  const int koff1 = (64 + (lg<<4)) ^ S;
  const int arow = (wm*64 + lr)*128;
  const int brow = (wn*64 + lr)*128;

  f32x4 acc[4][4];
  #pragma unroll
  for (int i=0;i<4;i++)
    #pragma unroll
    for (int j=0;j<4;j++) acc[i][j] = (f32x4){0.f,0.f,0.f,0.f};

  for (int t=0; t<nt; ++t){
    #pragma unroll
    for (int q=0;q<4;q++){
      __builtin_amdgcn_global_load_lds(
        (const __attribute__((address_space(1))) void*)((const char*)Ag + aoff + q*65536 + (size_t)t*128),
        (__attribute__((address_space(3))) void*)((char*)sA + ldst + q*4096), 16, 0, 0);
      __builtin_amdgcn_global_load_lds(
        (const __attribute__((address_space(1))) void*)((const char*)Bq + boff + q*65536 + (size_t)t*128),
        (__attribute__((address_space(3))) void*)((char*)sB + ldst + q*4096), 16, 0, 0);
    }
    __syncthreads();
    {
      bf16x8 a[4], b[4];
      #pragma unroll
      for (int m=0;m<4;m++) a[m] = RD(sA, arow + m*2048 + koff0);
      #pragma unroll
      for (int n=0;n<4;n++) b[n] = RD(sB, brow + n*2048 + koff0);
      #pragma unroll
      for (int m=0;m<4;m++)
        #pragma unroll
        for (int n=0;n<4;n++)
          acc[m][n] = __builtin_amdgcn_mfma_f32_16x16x32_bf16(a[m], b[n], acc[m][n], 0,0,0);
      #pragma unroll
      for (int m=0;m<4;m++) a[m] = RD(sA, arow + m*2048 + koff1);
      #pragma unroll
      for (int n=0;n<4;n++) b[n] = RD(sB, brow + n*2048 + koff1);
      #pragma unroll
      for (int m=0;m<4;m++)
        #pragma unroll
        for (int n=0;n<4;n++)
          acc[m][n] = __builtin_amdgcn_mfma_f32_16x16x32_bf16(a[m], b[n], acc[m][n], 0,0,0);
    }
    __syncthreads();
  }

  #pragma unroll
  for (int mi=0; mi<4; ++mi){
    #pragma unroll
    for (int ni=0; ni<4; ++ni){
      const int col = bn0 + wn*64 + ni*16 + lr;
      const float sc = bscale[col];
      const int rowb = bm0 + wm*64 + mi*16 + lg*4;
      const f32x4 a = acc[mi][ni];
      if (bn0 < 1024){
        #pragma unroll
        for (int r2=0;r2<4;r2++){
          const float val = a[r2]*sc;
          o_r[(size_t)(rowb+r2)*DM + col] = f2bf(1.f/(1.f+expf(-val)));
        }
      } else {
        const int dv = (col - 1024) >> 1;
        #pragma unroll
        for (int r2=0;r2<4;r2++){
          const float val = a[r2]*sc;
          const float pr  = val * __shfl_xor(val, 1);
          if (!(lr & 1))
            o_kv[(size_t)(rowb+r2)*DM + dv] = f2bf(pr);
        }
      }
    }
  }
}

// ---------------- K6: i8 GEMM for the Wo projection (2x MFMA rate, exact i32 acc) ----
#define RD8(base, off) (*(const i32x4*)((const char*)(base) + (off)))

__global__ __launch_bounds__(256, 4)
void gemm_o8(const signed char* __restrict__ Ag, const signed char* __restrict__ Bq,
             const float* __restrict__ bscale, const float* __restrict__ sxr,
             float* __restrict__ o_f)
{
  __shared__ signed char sA[128*128];           // 16KB
  __shared__ signed char sB[128*128];           // 16KB
  const int tid = threadIdx.x, wave = tid>>6, lane = tid&63;
  const int lr = lane&15, lg = lane>>4;
  const int wm = wave>>1, wn = wave&1;
  const int bm0 = blockIdx.x*128, bn0 = blockIdx.y*128;
  constexpr int nt = 8;                         // K = 1024 i8 / 128B

  const int r8   = lane>>3;
  const int scol = ((lane&7)<<4) ^ (r8<<4);
  const size_t aoff = (size_t)(bm0 + wave*8 + r8)*1024 + scol;
  const size_t boff = (size_t)(bn0 + wave*8 + r8)*1024 + scol;
  const int ldst = wave*1024;

  const int S = (lr&7)<<4;
  const int koff0 = ((lg<<4)     ) ^ S;
  const int koff1 = (64 + (lg<<4)) ^ S;
  const int arow = (wm*64 + lr)*128;
  const int brow = (wn*64 + lr)*128;

  i32x4 acc[4][4];
  #pragma unroll
  for (int i=0;i<4;i++)
    #pragma unroll
    for (int j=0;j<4;j++) acc[i][j] = (i32x4){0,0,0,0};

  for (int t=0; t<nt; ++t){
    #pragma unroll
    for (int q=0;q<4;q++){
      __builtin_amdgcn_global_load_lds(
        (const __attribute__((address_space(1))) void*)((const char*)Ag + aoff + q*32768 + (size_t)t*128),
        (__attribute__((address_space(3))) void*)((char*)sA + ldst + q*4096), 16, 0, 0);
      __builtin_amdgcn_global_load_lds(
        (const __attribute__((address_space(1))) void*)((const char*)Bq + boff + q*32768 + (size_t)t*128),
        (__attribute__((address_space(3))) void*)((char*)sB + ldst + q*4096), 16, 0, 0);
    }
    __syncthreads();
    {
      i32x4 a[4], b[4];
      #pragma unroll
      for (int m=0;m<4;m++) a[m] = RD8(sA, arow + m*2048 + koff0);
      #pragma unroll
      for (int n=0;n<4;n++) b[n] = RD8(sB, brow + n*2048 + koff0);
      #pragma unroll
      for (int m=0;m<4;m++)
        #pragma unroll
        for (int n=0;n<4;n++)
          acc[m][n] = __builtin_amdgcn_mfma_i32_16x16x64_i8(a[m], b[n], acc[m][n], 0,0,0);
      #pragma unroll
      for (int m=0;m<4;m++) a[m] = RD8(sA, arow + m*2048 + koff1);
      #pragma unroll
      for (int n=0;n<4;n++) b[n] = RD8(sB, brow + n*2048 + koff1);
      #pragma unroll
      for (int m=0;m<4;m++)
        #pragma unroll
        for (int n=0;n<4;n++)
          acc[m][n] = __builtin_amdgcn_mfma_i32_16x16x64_i8(a[m], b[n], acc[m][n], 0,0,0);
    }
    __syncthreads();
  }

  #pragma unroll
  for (int mi=0; mi<4; ++mi){
    const int rowb = bm0 + wm*64 + mi*16 + lg*4;
    float sx[4];
    #pragma unroll
    for (int r2=0;r2<4;r2++) sx[r2] = sxr[rowb+r2];
    #pragma unroll
    for (int ni=0; ni<4; ++ni){
      const int col = bn0 + wn*64 + ni*16 + lr;
      const float sc = bscale[col];
      const i32x4 a = acc[mi][ni];
      #pragma unroll
      for (int r2=0;r2<4;r2++)
        o_f[(size_t)(rowb+r2)*DM + col] = (float)a[r2] * sx[r2] * sc;
    }
  }
}

// ---------------- K3: per-chunk sums via reciprocal chain (no div/expf per t) -------
__global__ __launch_bounds__(256)
void kv_phase1(const u16* __restrict__ kv, const float* __restrict__ decay,
               float* __restrict__ part)
{
  const int c = blockIdx.x & 127, b = blockIdx.x >> 7;
  const int d0 = threadIdx.x*4;
  float rc[4], E1i[4]; f32x4 sum = {0.f,0.f,0.f,0.f};
  #pragma unroll
  for (int j=0;j<4;j++){
    const float dec = 1.f/(1.f+expf(-decay[d0+j]));
    const float ld  = logf(fmaxf(dec, 1e-7f));
    E1i[j] = expf(-ld);
    rc[j]  = expf(-(float)(c*32)*ld);           // 1/e at chunk start (inf ok -> clipped)
  }
  for (int t=c*32; t<c*32+32; ++t){
    const size_t base = ((size_t)(b*4096 + t))*DM + d0;
    const u16x4 p4 = *(const u16x4*)&kv[base];
    #pragma unroll
    for (int j=0;j<4;j++){
      sum[j] += bf2f(p4[j]) * fminf(rc[j], 1e10f);
      rc[j] *= E1i[j];
    }
  }
  *(f32x4*)&part[((size_t)(b*128+c))*DM + d0] = sum;
}

// ---------------- K4: exclusive prefix over 128 chunk sums (16-wide batches) --------
__global__ void chunk_prefix(float* __restrict__ part){
  const int g = blockIdx.x*256 + threadIdx.x;  // 0..4095
  const int b = g >> 10, d = g & 1023;
  float run = 0.f;
  for (int c16=0; c16<128; c16+=16){
    float v[16];
    #pragma unroll
    for (int i=0;i<16;i++)
      v[i] = part[((size_t)(b*128+c16+i))*DM + d];
    #pragma unroll
    for (int i=0;i<16;i++){
      const float tmp = v[i];
      part[((size_t)(b*128+c16+i))*DM + d] = run;
      run += tmp;                               // ascending order (bit-exact)
    }
  }
}

// ---------------- K5: scan (chained e, rc) + y=r*state + rmsnorm -> i8 yn -----------
__global__ __launch_bounds__(256)
void scan_norm(const u16* __restrict__ kv, const u16* __restrict__ rbuf,
               const float* __restrict__ part, const float* __restrict__ decay,
               const float* __restrict__ lnw, signed char* __restrict__ yn8,
               float* __restrict__ sxr)
{
  const int c = blockIdx.x & 127, b = blockIdx.x >> 7;
  const int tid = threadIdx.x, lane = tid&63, wave = tid>>6;
  const int d0 = tid*4;
  __shared__ float redS[2][4];
  __shared__ float redM[2][4];
  f32x4 run = *(const f32x4*)&part[((size_t)(b*128+c))*DM + d0];
  float lw[4], e[4], E1[4], rc[4], E1i[4];
  #pragma unroll
  for (int j=0;j<4;j++){
    const float dec = 1.f/(1.f+expf(-decay[d0+j]));
    const float ld  = logf(fmaxf(dec, 1e-7f));
    lw[j]  = lnw[d0+j];
    E1[j]  = expf(ld);
    E1i[j] = expf(-ld);
    e[j]   = expf((float)(c*32)*ld);            // underflows to 0 like ref
    rc[j]  = expf(-(float)(c*32)*ld);           // inf ok -> clipped
  }
  for (int t=c*32; t<c*32+32; ++t){
    const size_t base = ((size_t)(b*4096+t))*DM + d0;
    const u16x4 p4 = *(const u16x4*)&kv[base];
    const u16x4 r4 = *(const u16x4*)&rbuf[base];
    float yl[4]; float ss = 0.f, mx = 0.f;
    #pragma unroll
    for (int j=0;j<4;j++){
      run[j] += bf2f(p4[j]) * fminf(rc[j], 1e10f);
      const float st = run[j]*e[j];             // chained e: monotone underflow to 0
      const float y = bf2f(r4[j])*st;
      ss += y*y;
      yl[j] = y*lw[j];
      mx = fmaxf(mx, fabsf(yl[j]));
      rc[j] *= E1i[j];
      e[j]  *= E1[j];
    }
    #pragma unroll
    for (int off=32; off; off>>=1){
      ss += __shfl_down(ss, off);
      mx  = fmaxf(mx, __shfl_down(mx, off));
    }
    if (lane==0){ redS[t&1][wave] = ss; redM[t&1][wave] = mx; }
    __builtin_amdgcn_s_barrier();
    const float tot = (redS[t&1][0]+redS[t&1][1])+(redS[t&1][2]+redS[t&1][3]);
    const float m1  = fmaxf(fmaxf(redM[t&1][0],redM[t&1][1]),
                            fmaxf(redM[t&1][2],redM[t&1][3]));
    const float rs  = 1.f/sqrtf(tot*(1.f/1024.f) + 1e-6f);
    const float m1s = fmaxf(m1, 1e-30f);
    const float qk  = 127.f/m1s;
    if (tid==0) sxr[b*4096+t] = m1s*rs*(1.f/127.f);
    unsigned int p = 0;
    #pragma unroll
    for (int j=0;j<4;j++){
      int q = (int)rintf(yl[j]*qk);
      q = q>127?127:(q<-127?-127:q);
      p |= ((unsigned)(q&0xFF)) << (8*j);
    }
    *(unsigned int*)&yn8[base] = p;
  }
}

extern "C" void kernel_launch(void* const* d_in, const int* in_sizes, int n_in,
                              void* d_out, int out_size, void* d_ws, size_t ws_size,
                              hipStream_t stream)
{
  (void)in_sizes; (void)n_in; (void)out_size; (void)ws_size;
  const float* x    = (const float*)d_in[0];
  const float* Wr   = (const float*)d_in[1];
  const float* Wk   = (const float*)d_in[2];
  const float* Wv   = (const float*)d_in[3];
  const float* Wo   = (const float*)d_in[4];
  const float* dec  = (const float*)d_in[5];
  const float* lnw  = (const float*)d_in[6];

  // layout: wq 6MB | wq8 1MB | wsc 16KB | rbuf 33.5MB | kvbuf 33.5MB | part 2MB |
  //         xb 33.5MB | yn8 16.8MB | sxr 64KB
  char* ws = (char*)d_ws;
  u16*         wq    = (u16*)(ws + 0);
  signed char* wq8   = (signed char*)(ws + 6291456);
  float*       wsc   = (float*)(ws + 7340032);
  u16*         rbuf  = (u16*)(ws + 7356416);
  u16*         kvbuf = (u16*)(ws + 40910848);
  float*       part  = (float*)(ws + 74465280);
  u16*         xb    = (u16*)(ws + 76562432);
  signed char* yn8   = (signed char*)(ws + 110116864);
  float*       sxr   = (float*)(ws + 126894080);   // ends 126,959,616

  init_pack<<<17408, 256, 0, stream>>>(Wr, Wk, Wv, Wo, x, wq, wq8, wsc, xb);
  gemm_rkv<<<dim3(128,24), 256, 0, stream>>>(xb, wq, wsc, rbuf, kvbuf);
  kv_phase1<<<512, 256, 0, stream>>>(kvbuf, dec, part);
  chunk_prefix<<<16, 256, 0, stream>>>(part);
  scan_norm<<<512, 256, 0, stream>>>(kvbuf, rbuf, part, dec, lnw, yn8, sxr);
  gemm_o8<<<dim3(128,8), 256, 0, stream>>>(yn8, wq8, wsc + 3072, sxr, (float*)d_out);
}